// Round 3
// baseline (380.616 us; speedup 1.0000x reference)
//
#include <hip/hip_runtime.h>
#include <hip/hip_bf16.h>

#define N_IMG 32
#define CIN   128
#define INH   64
#define INW   64
#define COUT  256
#define OH    62
#define OW    62

typedef short          bf16x8 __attribute__((ext_vector_type(8)));
typedef unsigned short u16x8  __attribute__((ext_vector_type(8)));
typedef float          f32x16 __attribute__((ext_vector_type(16)));

__device__ __forceinline__ unsigned short f2bf(float x) {
    unsigned int u = __float_as_uint(x);
    u += 0x7fffu + ((u >> 16) & 1u);   // RNE
    return (unsigned short)(u >> 16);
}

// async global->LDS, 16B/lane; LDS arg must be the wave-uniform base
__device__ __forceinline__ void gl2lds16(const unsigned short* g, unsigned short* l) {
    __builtin_amdgcn_global_load_lds(
        (const __attribute__((address_space(1))) unsigned int*)g,
        (__attribute__((address_space(3))) unsigned int*)l,
        16, 0, 0);
}

// WT layout: [khw(9)][cg(16)][co(256)][i(8)] bf16, ci = cg*8 + i.
__global__ void wt_transform_kernel(const float* __restrict__ Wsrc,
                                    unsigned short* __restrict__ WT) {
    int idx = blockIdx.x * 256 + threadIdx.x;          // < 294912
    int i   = idx & 7;
    int co  = (idx >> 3) & 255;
    int cgk = idx >> 11;
    int cg  = cgk & 15;
    int khw = cgk >> 4;
    int kh  = khw / 3, kw = khw - 3 * kh;
    int ci  = cg * 8 + i;
    WT[idx] = f2bf(Wsrc[co * (CIN * 9) + ci * 9 + kh * 3 + kw]);
}

// Input pre-pass: f32 NCHW -> bf16 InT[img][ih][iw][ci], LINEAR (no swizzle;
// the conv staging gather applies the bank swizzle). Writes are block-contiguous:
// thread t writes 16B at block_base + t*16.
__global__ void in_transform_kernel(const float* __restrict__ In,
                                    unsigned short* __restrict__ InT) {
    const int q   = blockIdx.x;        // iw quarter 0..3
    const int ih  = blockIdx.y;
    const int img = blockIdx.z;
    const int t   = threadIdx.x;
    const int c   = t & 15;            // ci chunk 0..15
    const int iwl = t >> 4;            // 0..15
    const int iw  = q * 16 + iwl;
    const float* ip = In + (((size_t)img * CIN + c * 8) * INH + ih) * INW + iw;
    u16x8 v;
#pragma unroll
    for (int j = 0; j < 8; ++j) v[j] = f2bf(ip[(size_t)j * INH * INW]);
    unsigned short* op = InT + (((size_t)(img * INH + ih) * INW) + q * 16) * CIN;
    *(u16x8*)(op + t * 8) = v;
}

// Conv: block = (ow-half, oh-pair, img). 4 waves; wave w: co in [64w,64w+64).
// Per wave: m=64 co, n=64 (2 oh x 32 ow). Stage 4 rows x 36 iw x 128 ci bf16
// (36.9KB) via global_load_lds (swizzle applied in the gather), ONE barrier,
// then 4cb x 9 taps x 8 MFMA(32x32x16). acc = 64 regs -> 4 waves/SIMD.
__global__ __launch_bounds__(256, 4)
void conv_mfma32_kernel(const unsigned short* __restrict__ InT,
                        const unsigned short* __restrict__ WT,
                        float* __restrict__ Out) {
    // 4 rows, rowstride 38 iw x 128 ci shorts = 4864 shorts (9728B); total 38912B
    __shared__ __align__(16) unsigned short Lin[4 * 4864];

    const int half = blockIdx.x;       // 0,1
    const int oh0  = blockIdx.y * 2;
    const int img  = blockIdx.z;
    const int tid  = threadIdx.x;
    const int wave = tid >> 6;
    const int lane = tid & 63;
    const int h    = lane >> 5;        // k-half
    const int m32  = lane & 31;
    const int co_base = wave * 64;
    const int iw0  = half ? 28 : 0;

    // ---- stage: 2304 16B chunks = 9 issues/thread; swizzled gather ----
    {
        const unsigned short* gbase =
            InT + (((size_t)img * INH + oh0) * INW) * CIN;
#pragma unroll
        for (int i = 0; i < 9; ++i) {
            const int k0   = i * 256 + (tid & 192);   // wave-uniform chunk base
            const int r    = k0 / 576;                // row 0..3 (no mid-wave cross)
            const int off0 = k0 - r * 576;
            const int off  = off0 + lane;             // < 576
            const int liw  = off >> 4;
            const int c    = off & 15;
            const int iw   = iw0 + liw;
            const int cf   = c ^ (iw & 15);
            gl2lds16(gbase + (size_t)r * (INW * CIN) + iw * CIN + cf * 8,
                     Lin + r * 4864 + off0 * 8);
        }
    }
    __syncthreads();

    f32x16 acc[2][2];   // [oh][mi]
#pragma unroll
    for (int a = 0; a < 2; ++a)
#pragma unroll
        for (int b = 0; b < 2; ++b)
#pragma unroll
            for (int g = 0; g < 16; ++g) acc[a][b][g] = 0.f;

    const bf16x8* WTv = (const bf16x8*)WT;
    const int liw_b = m32 + (half ? 4 : 0);
    const int swz_b = m32 & 15;  // (m32+kw)&15 computed per tap

    for (int cb = 0; cb < 4; ++cb) {
#pragma unroll
        for (int kh = 0; kh < 3; ++kh) {
#pragma unroll
            for (int kw = 0; kw < 3; ++kw) {
                const int khw = kh * 3 + kw;
                bf16x8 wf[2][2];   // [mi][kc]
#pragma unroll
                for (int mi = 0; mi < 2; ++mi)
#pragma unroll
                    for (int kc = 0; kc < 2; ++kc)
                        wf[mi][kc] = WTv[(khw * 16 + cb * 4 + kc * 2 + h) * 256 +
                                         co_base + mi * 32 + m32];
                bf16x8 xf[2][2];   // [oi][kc]
                const int liw = liw_b + kw;
                const int swz = (m32 + kw) & 15;
#pragma unroll
                for (int oi = 0; oi < 2; ++oi) {
                    const int r = oi + kh;
#pragma unroll
                    for (int kc = 0; kc < 2; ++kc) {
                        const int cf = cb * 4 + kc * 2 + h;
                        xf[oi][kc] = *(const bf16x8*)&Lin[r * 4864 + liw * 128 +
                                                          ((cf ^ swz) * 8)];
                    }
                }
#pragma unroll
                for (int oi = 0; oi < 2; ++oi)
#pragma unroll
                    for (int mi = 0; mi < 2; ++mi)
#pragma unroll
                        for (int kc = 0; kc < 2; ++kc)
                            acc[oi][mi] = __builtin_amdgcn_mfma_f32_32x32x16_bf16(
                                wf[mi][kc], xf[oi][kc], acc[oi][mi], 0, 0, 0);
            }
        }
    }

    // ---- epilogue: col=lane&31 -> ow, row=(g&3)+8*(g>>2)+4*h -> co ----
    const int ow = half * 32 + m32;
#pragma unroll
    for (int oi = 0; oi < 2; ++oi) {
        const int oh = oh0 + oi;
#pragma unroll
        for (int mi = 0; mi < 2; ++mi) {
#pragma unroll
            for (int g = 0; g < 16; ++g) {
                const int rr = (g & 3) + 8 * (g >> 2) + 4 * h;
                const int co = co_base + mi * 32 + rr;
                if (ow < OW)
                    Out[(((size_t)img * COUT + co) * OH + oh) * OW + ow] =
                        acc[oi][mi][g];
            }
        }
    }
}

// ---------- fallback: naive (only if workspace is tiny) ----------
__global__ void conv_naive_kernel(const float* __restrict__ In,
                                  const float* __restrict__ Wt,
                                  float* __restrict__ Out) {
    int idx = blockIdx.x * 256 + threadIdx.x;
    const int total = N_IMG * COUT * OH * OW;
    if (idx >= total) return;
    int ow = idx % OW; int t = idx / OW;
    int oh = t % OH;   t /= OH;
    int co = t % COUT; int img = t / COUT;
    float s = 0.f;
    for (int ci = 0; ci < CIN; ++ci)
#pragma unroll
        for (int kh = 0; kh < 3; ++kh)
#pragma unroll
            for (int kw = 0; kw < 3; ++kw)
                s += In[((size_t)(img * CIN + ci) * INH + oh + kh) * INW + ow + kw] *
                     Wt[co * CIN * 9 + ci * 9 + kh * 3 + kw];
    Out[idx] = s;
}

extern "C" void kernel_launch(void* const* d_in, const int* in_sizes, int n_in,
                              void* d_out, int out_size, void* d_ws, size_t ws_size,
                              hipStream_t stream) {
    const float* In   = (const float*)d_in[0];
    const float* Wsrc = (const float*)d_in[1];
    float* Out        = (float*)d_out;

    const size_t INT_OFF   = 1u << 20;                                         // WT at 0
    const size_t INT_BYTES = (size_t)N_IMG * INH * INW * CIN * sizeof(unsigned short);

    if (ws_size >= INT_OFF + INT_BYTES) {
        unsigned short* WT  = (unsigned short*)d_ws;
        unsigned short* InT = (unsigned short*)((char*)d_ws + INT_OFF);
        wt_transform_kernel<<<dim3(294912 / 256), dim3(256), 0, stream>>>(Wsrc, WT);
        in_transform_kernel<<<dim3(4, INH, N_IMG), dim3(256), 0, stream>>>(In, InT);
        conv_mfma32_kernel<<<dim3(2, OH / 2, N_IMG), dim3(256), 0, stream>>>(InT, WT, Out);
    } else {
        const int total = N_IMG * COUT * OH * OW;
        conv_naive_kernel<<<dim3((total + 255) / 256), dim3(256), 0, stream>>>(In, Wsrc, Out);
    }
}

// Round 4
// 325.315 us; speedup vs baseline: 1.1700x; 1.1700x over previous
//
#include <hip/hip_runtime.h>
#include <hip/hip_bf16.h>

#define N_IMG 32
#define CIN   128
#define INH   64
#define INW   64
#define COUT  256
#define OH    62
#define OW    62

typedef short          bf16x8 __attribute__((ext_vector_type(8)));
typedef unsigned short u16x8  __attribute__((ext_vector_type(8)));
typedef float          f32x16 __attribute__((ext_vector_type(16)));

__device__ __forceinline__ unsigned short f2bf(float x) {
    unsigned int u = __float_as_uint(x);
    u += 0x7fffu + ((u >> 16) & 1u);   // RNE
    return (unsigned short)(u >> 16);
}

// async global->LDS, 16B/lane; LDS arg must be the wave-uniform base
__device__ __forceinline__ void gl2lds16(const unsigned short* g, unsigned short* l) {
    __builtin_amdgcn_global_load_lds(
        (const __attribute__((address_space(1))) unsigned int*)g,
        (__attribute__((address_space(3))) unsigned int*)l,
        16, 0, 0);
}

// WT layout: [khw(9)][cg(16)][co(256)][i(8)] bf16, ci = cg*8 + i.
__global__ void wt_transform_kernel(const float* __restrict__ Wsrc,
                                    unsigned short* __restrict__ WT) {
    int idx = blockIdx.x * 256 + threadIdx.x;          // < 294912
    int i   = idx & 7;
    int co  = (idx >> 3) & 255;
    int cgk = idx >> 11;
    int cg  = cgk & 15;
    int khw = cgk >> 4;
    int kh  = khw / 3, kw = khw - 3 * kh;
    int ci  = cg * 8 + i;
    WT[idx] = f2bf(Wsrc[co * (CIN * 9) + ci * 9 + kh * 3 + kw]);
}

// Input pre-pass: f32 NCHW -> bf16 InT[img][ih][iw][ci], LINEAR layout.
// Fully coalesced writes: thread t writes 16B at block_base + t*16.
__global__ void in_transform_kernel(const float* __restrict__ In,
                                    unsigned short* __restrict__ InT) {
    const int q   = blockIdx.x;        // iw quarter 0..3
    const int ih  = blockIdx.y;
    const int img = blockIdx.z;
    const int t   = threadIdx.x;
    const int c   = t & 15;            // ci chunk 0..15
    const int iwl = t >> 4;            // 0..15
    const int iw  = q * 16 + iwl;
    const float* ip = In + (((size_t)img * CIN + c * 8) * INH + ih) * INW + iw;
    u16x8 v;
#pragma unroll
    for (int j = 0; j < 8; ++j) v[j] = f2bf(ip[(size_t)j * INH * INW]);
    unsigned short* op = InT + (((size_t)(img * INH + ih) * INW) + q * 16) * CIN;
    *(u16x8*)(op + t * 8) = v;
}

// Conv: block = (oh, img), 4 waves; wave w: co in [64w,64w+64), full 62-ow row.
// K is processed in 4 chunks of 32 ci; each chunk's input slab (3 rows x 64 iw
// x 32 ci bf16 = 12KB) is staged via global_load_lds, double-buffered: loads
// for chunk cb+1 issue right after the barrier and overlap chunk cb's 72 MFMAs.
// acc = 64 AGPR, ~64 VGPR -> 4 waves/SIMD; LDS 24.7KB.
__global__ __launch_bounds__(256, 4)
void conv_mfma32_kernel(const unsigned short* __restrict__ InT,
                        const unsigned short* __restrict__ WT,
                        float* __restrict__ Out) {
    // per buffer: 3 rows x 64 iw x 4 chunks x 8 bf16 = 6144 shorts (12KB).
    // +64 guard shorts: B-frag reads at iw=64,65 (lanes with ow>=62, results
    // discarded) run past the row block; keep them in-bounds.
    __shared__ __align__(16) unsigned short Lin[2 * 6144 + 64];

    const int oh   = blockIdx.x;
    const int img  = blockIdx.y;
    const int tid  = threadIdx.x;
    const int wave = tid >> 6;
    const int lane = tid & 63;
    const int h    = lane >> 5;        // k-half of the 32x32x16 MFMA
    const int m32  = lane & 31;
    const int co_base = wave * 64;

    const unsigned short* gIn = InT + ((size_t)(img * INH + oh) * INW) * CIN;

    // chunk (r, iw, c) stored at position ((r*64+iw)*4 + (c ^ (iw&3))) * 16B:
    // read side lands 2 lanes/bank (free); staging global side stays within
    // 64B lines (c-permutation inside the 256B ci-row).
    const int s_iwl = lane >> 2;       // 0..15
    const int s_cs  = lane & 3;        // swizzled chunk position

#define STAGE(cb, bi)                                                          \
    {                                                                          \
        _Pragma("unroll")                                                      \
        for (int i = 0; i < 3; ++i) {                                          \
            const int b  = i * 4 + wave;          /* 0..11, wave-uniform */    \
            const int r  = b >> 2;                                             \
            const int iw = ((b & 3) << 4) + s_iwl;                             \
            const int c  = s_cs ^ (iw & 3);                                    \
            gl2lds16(gIn + (size_t)r * (INW * CIN) + iw * CIN + ((cb)*4 + c)*8,\
                     Lin + (bi) * 6144 + b * 512);                             \
        }                                                                      \
    }

    STAGE(0, 0);

    f32x16 acc[2][2];   // [mi][ni]
#pragma unroll
    for (int a = 0; a < 2; ++a)
#pragma unroll
        for (int b = 0; b < 2; ++b)
#pragma unroll
            for (int g = 0; g < 16; ++g) acc[a][b][g] = 0.f;

    const bf16x8* WTv = (const bf16x8*)WT;

    for (int cb = 0; cb < 4; ++cb) {
        const int bi = cb & 1;
        __syncthreads();                       // buffer bi ready (vmcnt drained)
        if (cb < 3) STAGE(cb + 1, bi ^ 1);     // overlap next chunk's staging
#pragma unroll
        for (int kh = 0; kh < 3; ++kh) {
#pragma unroll
            for (int kw = 0; kw < 3; ++kw) {
                const int khw = kh * 3 + kw;
                bf16x8 wf[2][2];   // [mi][kc]
#pragma unroll
                for (int mi = 0; mi < 2; ++mi)
#pragma unroll
                    for (int kc = 0; kc < 2; ++kc)
                        wf[mi][kc] = WTv[(khw * 16 + cb * 4 + kc * 2 + h) * 256 +
                                         co_base + mi * 32 + m32];
                bf16x8 xf[2][2];   // [ni][kc]
#pragma unroll
                for (int ni = 0; ni < 2; ++ni) {
                    const int iw = ni * 32 + m32 + kw;
#pragma unroll
                    for (int kc = 0; kc < 2; ++kc) {
                        const int p = (kh * 64 + iw) * 4 + ((kc * 2 + h) ^ (iw & 3));
                        xf[ni][kc] = *(const bf16x8*)&Lin[bi * 6144 + p * 8];
                    }
                }
#pragma unroll
                for (int mi = 0; mi < 2; ++mi)
#pragma unroll
                    for (int ni = 0; ni < 2; ++ni)
#pragma unroll
                        for (int kc = 0; kc < 2; ++kc)
                            acc[mi][ni] = __builtin_amdgcn_mfma_f32_32x32x16_bf16(
                                wf[mi][kc], xf[ni][kc], acc[mi][ni], 0, 0, 0);
            }
        }
    }
#undef STAGE

    // epilogue: col=lane&31 -> ow, row=(g&3)+8*(g>>2)+4*h -> co; full-row writes
#pragma unroll
    for (int mi = 0; mi < 2; ++mi) {
#pragma unroll
        for (int g = 0; g < 16; ++g) {
            const int rr = (g & 3) + 8 * (g >> 2) + 4 * h;
            const int co = co_base + mi * 32 + rr;
            float* op = Out + (((size_t)img * COUT + co) * OH + oh) * OW;
            op[m32] = acc[mi][0][g];
            if (m32 < OW - 32) op[32 + m32] = acc[mi][1][g];
        }
    }
}

// ---------- fallback: naive (only if workspace is tiny) ----------
__global__ void conv_naive_kernel(const float* __restrict__ In,
                                  const float* __restrict__ Wt,
                                  float* __restrict__ Out) {
    int idx = blockIdx.x * 256 + threadIdx.x;
    const int total = N_IMG * COUT * OH * OW;
    if (idx >= total) return;
    int ow = idx % OW; int t = idx / OW;
    int oh = t % OH;   t /= OH;
    int co = t % COUT; int img = t / COUT;
    float s = 0.f;
    for (int ci = 0; ci < CIN; ++ci)
#pragma unroll
        for (int kh = 0; kh < 3; ++kh)
#pragma unroll
            for (int kw = 0; kw < 3; ++kw)
                s += In[((size_t)(img * CIN + ci) * INH + oh + kh) * INW + ow + kw] *
                     Wt[co * CIN * 9 + ci * 9 + kh * 3 + kw];
    Out[idx] = s;
}

extern "C" void kernel_launch(void* const* d_in, const int* in_sizes, int n_in,
                              void* d_out, int out_size, void* d_ws, size_t ws_size,
                              hipStream_t stream) {
    const float* In   = (const float*)d_in[0];
    const float* Wsrc = (const float*)d_in[1];
    float* Out        = (float*)d_out;

    const size_t INT_OFF   = 1u << 20;   // WT lives at offset 0 (590KB)
    const size_t INT_BYTES = (size_t)N_IMG * INH * INW * CIN * sizeof(unsigned short);

    if (ws_size >= INT_OFF + INT_BYTES) {
        unsigned short* WT  = (unsigned short*)d_ws;
        unsigned short* InT = (unsigned short*)((char*)d_ws + INT_OFF);
        wt_transform_kernel<<<dim3(294912 / 256), dim3(256), 0, stream>>>(Wsrc, WT);
        in_transform_kernel<<<dim3(4, INH, N_IMG), dim3(256), 0, stream>>>(In, InT);
        conv_mfma32_kernel<<<dim3(OH, N_IMG), dim3(256), 0, stream>>>(InT, WT, Out);
    } else {
        const int total = N_IMG * COUT * OH * OW;
        conv_naive_kernel<<<dim3((total + 255) / 256), dim3(256), 0, stream>>>(In, Wsrc, Out);
    }
}